// Round 1
// baseline (135.141 us; speedup 1.0000x reference)
//
#include <hip/hip_runtime.h>
#include <math.h>

// HoughVoting on MI355X.
// P = 60x80 = 4800 subsampled pixels; 4800 candidate centers (same grid);
// K = 10 classes (class 0 dropped from output).
//
// Pipeline:
//   k_init  : zero cursors + hough/dsum accumulators + d_out (harness poisons 0xAA)
//   k_pixel : per-pixel u,v (normalized), d=exp(clip(z,-3,3)), counting-sort into
//             per-class bins (atomic cursor; within-class order nondeterministic —
//             only perturbs float dsum summation order, ~1e-5 rel, harmless)
//   k_vote  : per-(candidate, class, segment) accumulate inlier votes + dsum.
//             All dot-path arithmetic uses __f*_rn intrinsics to forbid FMA
//             contraction -> bit-exact match with XLA/NumPy CPU rounding, so the
//             dot>0.9 decisions and integer vote counts match the reference exactly.
//   k_final : first-occurrence argmax per class (matches jnp.argmax tie-break),
//             then box/pose epilogue with reference op ordering.

#define GX 80
#define GY 60
#define P_TOT 4800
#define EPSF 1e-6f
#define CAP 4800          // per-class bin capacity (safe upper bound)
#define NCLS 10

// ws layout in floats (total 326464 floats ~= 1.25 MB)
#define WS_CUR 0                      // 16 ints: per-class cursors
#define WS_BINS 64                    // 5 arrays of 10*CAP floats: u,v,d,px,py
#define BIN_STRIDE (NCLS * CAP)       // 48000
#define WS_HOUGH (WS_BINS + 5 * BIN_STRIDE)   // 240064, 9*4800 floats
#define WS_DSUM (WS_HOUGH + 9 * P_TOT)        // 283264, 9*4800 floats

__global__ void k_init(float* __restrict__ ws, float* __restrict__ out) {
    int t = blockIdx.x * blockDim.x + threadIdx.x;
    if (t < 16) ((int*)ws)[WS_CUR + t] = 0;
    if (t < 2 * 9 * P_TOT) ws[WS_HOUGH + t] = 0.0f;   // hough + dsum contiguous
    if (t < 855) out[t] = 0.0f;                        // all outputs default 0
}

__global__ void k_pixel(const int* __restrict__ label,
                        const float* __restrict__ vp,
                        float* __restrict__ ws) {
    int p = blockIdx.x * blockDim.x + threadIdx.x;
    if (p >= P_TOT) return;
    int i = p / GX, j = p - i * GX;
    int pyc = i * 8, pxc = j * 8;
    int lab = label[pyc * 640 + pxc];
    int* cur = (int*)ws + WS_CUR;
    int r = atomicAdd(&cur[lab], 1);
    int pos = lab * CAP + r;
    int base = (pyc * 640 + pxc) * 30 + 3 * lab;
    float u0 = vp[base], v0 = vp[base + 1], w = vp[base + 2];
    w = fminf(fmaxf(w, -3.0f), 3.0f);
    float d = expf(w);
    // nrm = sqrt(u*u + v*v) + EPS, every op rounded separately (no FMA)
    float nrm = __fadd_rn(
        __fsqrt_rn(__fadd_rn(__fmul_rn(u0, u0), __fmul_rn(v0, v0))), EPSF);
    float u = __fdiv_rn(u0, nrm);
    float v = __fdiv_rn(v0, nrm);
    float* bu = ws + WS_BINS;
    bu[pos] = u;
    bu[BIN_STRIDE + pos] = v;
    bu[2 * BIN_STRIDE + pos] = d;
    bu[3 * BIN_STRIDE + pos] = (float)pxc;
    bu[4 * BIN_STRIDE + pos] = (float)pyc;
}

#define CHUNK 128

__global__ __launch_bounds__(256) void k_vote(float* __restrict__ ws) {
    const int k = blockIdx.y + 1;           // class 1..9 (class 0 never votes)
    const int s = blockIdx.z;
    const int S = gridDim.z;
    const int* cur = (const int*)ws + WS_CUR;
    const int cntk = cur[k];
    const int tid = threadIdx.x;
    const int c = blockIdx.x * 256 + tid;   // candidate index (this thread)
    int ci = c / GX, cj = c - ci * GX;
    float cxf = (float)(cj * 8), cyf = (float)(ci * 8);

    const float* bu = ws + WS_BINS + k * CAP;
    const float* bv = bu + BIN_STRIDE;
    const float* bd = bu + 2 * BIN_STRIDE;
    const float* bx = bu + 3 * BIN_STRIDE;
    const float* by = bu + 4 * BIN_STRIDE;

    __shared__ float su[CHUNK], sv[CHUNK], sd[CHUNK], sx[CHUNK], sy[CHUNK];
    float accn = 0.0f, accd = 0.0f;

    for (int base = s * CHUNK; base < cntk; base += S * CHUNK) {
        int m = min(CHUNK, cntk - base);
        if (tid < m) {
            su[tid] = bu[base + tid];
            sv[tid] = bv[base + tid];
            sd[tid] = bd[base + tid];
            sx[tid] = bx[base + tid];
            sy[tid] = by[base + tid];
        }
        __syncthreads();
        #pragma unroll 4
        for (int p = 0; p < m; ++p) {
            // dx,dy,rd2 are exact small integers in fp32; sqrt correctly rounded.
            float dx = __fsub_rn(cxf, sx[p]);
            float dy = __fsub_rn(cyf, sy[p]);
            float rd2 = __fadd_rn(__fmul_rn(dx, dx), __fmul_rn(dy, dy));
            float rd = __fadd_rn(__fsqrt_rn(rd2), EPSF);
            float num = __fadd_rn(__fmul_rn(su[p], dx), __fmul_rn(sv[p], dy));
            float dot = __fdiv_rn(num, rd);
            if (dot > 0.9f) {
                accn += 1.0f;
                accd += sd[p];
            }
        }
        __syncthreads();
    }
    if (c < P_TOT) {
        atomicAdd(&ws[WS_HOUGH + (k - 1) * P_TOT + c], accn);
        atomicAdd(&ws[WS_DSUM + (k - 1) * P_TOT + c], accd);
    }
}

__global__ __launch_bounds__(256) void k_final(const float* __restrict__ ws,
                                               const float* __restrict__ extents,
                                               const float* __restrict__ meta,
                                               float* __restrict__ out) {
    const int k = blockIdx.x + 1;    // class 1..9 -> output row k-1
    const int tid = threadIdx.x;
    const float* hrow = ws + WS_HOUGH + (k - 1) * P_TOT;

    // first-occurrence argmax (strict > over increasing c)
    float best = -1.0f;
    int bidx = 0;
    for (int c = tid; c < P_TOT; c += 256) {
        float v = hrow[c];
        if (v > best) { best = v; bidx = c; }
    }
    __shared__ float svv[256];
    __shared__ int sii[256];
    svv[tid] = best;
    sii[tid] = bidx;
    __syncthreads();
    for (int off = 128; off > 0; off >>= 1) {
        if (tid < off) {
            float ov = svv[tid + off];
            int oi = sii[tid + off];
            if (ov > svv[tid] || (ov == svv[tid] && oi < sii[tid])) {
                svv[tid] = ov;
                sii[tid] = oi;
            }
        }
        __syncthreads();
    }
    if (tid == 0) {
        float votes = svv[0];
        int bc = sii[0];
        float dsv = ws[WS_DSUM + (k - 1) * P_TOT + bc];
        float davg = __fdiv_rn(dsv, fmaxf(votes, 1.0f));
        int ci = bc / GX, cj = bc - ci * GX;
        float cx = (float)(cj * 8), cy = (float)(ci * 8);
        const int* cur = (const int*)ws + WS_CUR;
        float countf = (float)cur[k];
        bool valid = (votes > 20.0f) &&
                     (votes > __fmul_rn(0.1f, countf)) &&
                     (__fmul_rn(__fmul_rn(countf, 8.0f), 8.0f) > 500.0f);
        float e0 = extents[k * 3 + 0], e1 = extents[k * 3 + 1], e2 = extents[k * 3 + 2];
        float diam = __fadd_rn(
            __fsqrt_rn(__fadd_rn(__fadd_rn(__fmul_rn(e0, e0), __fmul_rn(e1, e1)),
                                 __fmul_rn(e2, e2))),
            EPSF);
        float fx = meta[0], fy = meta[4], ppx = meta[2], ppy = meta[5];
        float dm = fmaxf(davg, EPSF);
        // hx = 0.5 * diam * fx / max(davg, EPS)  (left-assoc, per reference)
        float hx = __fdiv_rn(__fmul_rn(__fmul_rn(0.5f, diam), fx), dm);
        float hy = __fdiv_rn(__fmul_rn(__fmul_rn(0.5f, diam), fy), dm);
        float score = valid ? votes : 0.0f;
        float* brow = out + (k - 1) * 7;            // top_box [1,9,7], batch idx 0
        brow[0] = 0.0f;
        brow[1] = (float)k;
        brow[2] = __fsub_rn(cx, hx);
        brow[3] = __fsub_rn(cy, hy);
        brow[4] = __fadd_rn(cx, hx);
        brow[5] = __fadd_rn(cy, hy);
        brow[6] = score;
        float tx = __fdiv_rn(__fmul_rn(__fsub_rn(cx, ppx), davg), fx);
        float ty = __fdiv_rn(__fmul_rn(__fsub_rn(cy, ppy), davg), fy);
        float* prow = out + 63 + (k - 1) * 7;       // top_pose [1,9,7]
        prow[0] = 1.0f; prow[1] = 0.0f; prow[2] = 0.0f; prow[3] = 0.0f;
        prow[4] = tx; prow[5] = ty; prow[6] = davg;
    }
}

extern "C" void kernel_launch(void* const* d_in, const int* in_sizes, int n_in,
                              void* d_out, int out_size, void* d_ws, size_t ws_size,
                              hipStream_t stream) {
    const int* label = (const int*)d_in[0];       // [1,480,640] int32
    const float* vp = (const float*)d_in[1];      // [1,480,640,30] f32
    const float* extents = (const float*)d_in[2]; // [10,3] f32
    const float* meta = (const float*)d_in[4];    // [1,9] f32
    float* out = (float*)d_out;                   // 63+63+360+360+9 = 855
    float* ws = (float*)d_ws;

    hipLaunchKernelGGL(k_init, dim3(338), dim3(256), 0, stream, ws, out);
    hipLaunchKernelGGL(k_pixel, dim3(19), dim3(256), 0, stream, label, vp, ws);
    hipLaunchKernelGGL(k_vote, dim3(19, 9, 4), dim3(256), 0, stream, ws);
    hipLaunchKernelGGL(k_final, dim3(9), dim3(256), 0, stream, ws, extents, meta, out);
}